// Round 4
// baseline (128.016 us; speedup 1.0000x reference)
//
#include <hip/hip_runtime.h>

#define MM 576
#define NBLK 128    // 4n x 4t x 8s; <=256 so all blocks co-resident

__device__ __forceinline__ float lrelu(float x) { return x > 0.f ? x : 0.2f * x; }
__device__ __forceinline__ float elu1(float x)  { return x > 0.f ? x : (expf(x) - 1.f); }

// Device-scope (agent) coherent 4B accesses: write-through/bypass the
// non-coherent per-XCD L2, so cross-block data needs no L2 flush.
__device__ __forceinline__ void gstore(float* p, float v) {
    __hip_atomic_store(p, v, __ATOMIC_RELAXED, __HIP_MEMORY_SCOPE_AGENT);
}
__device__ __forceinline__ float gload(const float* p) {
    return __hip_atomic_load(const_cast<float*>(p), __ATOMIC_RELAXED, __HIP_MEMORY_SCOPE_AGENT);
}

// Grid barrier: one arrival RMW per block + load-only polling. All
// cross-block payload is agent-scope already, so the fences have ~no dirty
// L2 to write back (this was the 17us/barrier cost in round 3).
__device__ __forceinline__ void grid_barrier(unsigned* cnt, unsigned target) {
    __syncthreads();
    if (threadIdx.x == 0) {
        __threadfence();
        __hip_atomic_fetch_add(cnt, 1u, __ATOMIC_RELAXED, __HIP_MEMORY_SCOPE_AGENT);
        while (__hip_atomic_load(cnt, __ATOMIC_RELAXED, __HIP_MEMORY_SCOPE_AGENT) < target)
            __builtin_amdgcn_s_sleep(2);
        __threadfence();
    }
    __syncthreads();
}

struct SMem {
    float Wh[4][4][18][32];      // [hd][t'][row][v]  36 KB — lives across phases
    float xb[18][4][32];         // x / inter slice    9 KB — lives across layers
    union {
        struct { float red[8][4][2][32]; } p1;                       // 8 KB
        struct { float adj[1024]; float att[1024];
                 float e[4][2][32]; float wmin[4], wmax[4];
                 float d12[32]; } p2;                                // ~9.4 KB
        struct { float C[4][1024]; } p3;                             // 16 KB
    } u;
};                               // total ~62.5 KB static

// ---------------------------------------------------------------------------
// P1 (all 128 blocks, (n,t,s)): stage x slice (layer 1 only; layer 2 slice is
// already in xb), compute Wh for 4 heads x 4 t' x 18 rows into LDS, reduce the
// separable attention-logit partials and publish them (agent-scope).
// ---------------------------------------------------------------------------
__device__ void phase1(int n, int t, int s,
                       const float* __restrict__ xin,       // null for layer 2
                       const float* __restrict__ mw_l,
                       const float* __restrict__ mb_l,
                       const float* __restrict__ a_l,
                       float* __restrict__ epart,
                       SMem& sm) {
    int tid = threadIdx.x;
    if (xin) {
        const float* src = xin + (size_t)(n * MM + t * 144 + s * 18) * 128;
        float* dst = &sm.xb[0][0][0];
        for (int p = tid; p < 2304; p += 256) dst[p] = src[p];
    }
    __syncthreads();
    int sub = tid >> 5, v = tid & 31;
    for (int hd = 0; hd < 4; ++hd) {
        float w16[16], bb[4];
#pragma unroll
        for (int q = 0; q < 16; ++q) w16[q] = mw_l[hd * 16 + q];
#pragma unroll
        for (int q = 0; q < 4; ++q) bb[q] = mb_l[hd * 4 + q];
        float acci = 0.f, accj = 0.f;
        for (int r = sub; r < 18; r += 8) {          // wave-uniform trip counts
            int rr = s * 18 + r;
            int dh = rr / 24, wc = rr % 24;
            float4 aiv = *(const float4*)(a_l + hd * 1152 + dh * 192 + wc * 4);
            float4 ajv = *(const float4*)(a_l + hd * 1152 + 96 + dh * 192 + wc * 4);
            float ai[4] = {aiv.x, aiv.y, aiv.z, aiv.w};
            float aj[4] = {ajv.x, ajv.y, ajv.z, ajv.w};
            float x0 = sm.xb[r][0][v], x1 = sm.xb[r][1][v];
            float x2 = sm.xb[r][2][v], x3 = sm.xb[r][3][v];
#pragma unroll
            for (int tt = 0; tt < 4; ++tt) {
                float wh = fmaf(x0, w16[tt], fmaf(x1, w16[4 + tt],
                            fmaf(x2, w16[8 + tt], fmaf(x3, w16[12 + tt], bb[tt]))));
                sm.Wh[hd][tt][r][v] = wh;
                acci = fmaf(wh, ai[tt], acci);
                accj = fmaf(wh, aj[tt], accj);
            }
        }
        sm.u.p1.red[sub][hd][0][v] = acci;
        sm.u.p1.red[sub][hd][1][v] = accj;
    }
    __syncthreads();
    {   // reduce over the 8 row-groups; publish e-partial for (n,hd,q=t,s)
        int hd = tid >> 6, wh = (tid >> 5) & 1, vv = tid & 31;
        float e = 0.f;
#pragma unroll
        for (int ss = 0; ss < 8; ++ss) e += sm.u.p1.red[ss][hd][wh][vv];
        gstore(&epart[(((((size_t)n * 4 + hd) * 4 + t) * 8 + s) * 2 + wh) * 32 + vv], e);
    }
}

// ---------------------------------------------------------------------------
// P2 (blocks 0..63, (hd,n,t)): adjacency norm + softmax + C = att^T * adjn,
// published agent-scope (1024 floats per block).
// ---------------------------------------------------------------------------
__device__ void phase2(int hd, int n, int t, int layer,
                       const float* __restrict__ Bp,
                       const float* __restrict__ epart,
                       float* __restrict__ Cbuf,
                       SMem& sm) {
    int tid = threadIdx.x;
    const float* B = Bp + ((size_t)layer * 4 + hd) * 1024;
    float lmin = 1e30f, lmax = -1e30f;
    for (int p = tid; p < 1024; p += 256) {
        int i = p >> 5, j = p & 31;
        float val = B[p] + (i == j ? 1.f : 0.f);
        sm.u.p2.adj[p] = val;
        lmin = fminf(lmin, val);
        lmax = fmaxf(lmax, val);
    }
    {   // gather e over the 8 s-slices: thread = (q, which, v)
        int q = tid >> 6, wh = (tid >> 5) & 1, v = tid & 31;
        float e = 0.f;
        for (int ss = 0; ss < 8; ++ss)
            e += gload(&epart[(((((size_t)n * 4 + hd) * 4 + q) * 8 + ss) * 2 + wh) * 32 + v]);
        sm.u.p2.e[q][wh][v] = e;
    }
#pragma unroll
    for (int off = 32; off; off >>= 1) {
        lmin = fminf(lmin, __shfl_xor(lmin, off, 64));
        lmax = fmaxf(lmax, __shfl_xor(lmax, off, 64));
    }
    if ((tid & 63) == 0) { sm.u.p2.wmin[tid >> 6] = lmin; sm.u.p2.wmax[tid >> 6] = lmax; }
    __syncthreads();
    float mn = fminf(fminf(sm.u.p2.wmin[0], sm.u.p2.wmin[1]),
                     fminf(sm.u.p2.wmin[2], sm.u.p2.wmin[3]));
    float mx = fmaxf(fmaxf(sm.u.p2.wmax[0], sm.u.p2.wmax[1]),
                     fmaxf(sm.u.p2.wmax[2], sm.u.p2.wmax[3]));
    float inv = 1.f / (mx - mn);
    for (int p = tid; p < 1024; p += 256) sm.u.p2.adj[p] = (sm.u.p2.adj[p] - mn) * inv;
    __syncthreads();
    if (tid < 32) {  // row sums, rotated column access: conflict-free
        float ssum = 0.f;
        for (int j = 0; j < 32; ++j) ssum += sm.u.p2.adj[tid * 32 + ((j + tid) & 31)];
        sm.u.p2.d12[tid] = rsqrtf(ssum);
    }
    __syncthreads();
    for (int p = tid; p < 1024; p += 256) {
        int i = p >> 5, j = p & 31;
        sm.u.p2.adj[p] = sm.u.p2.d12[i] * sm.u.p2.adj[p] * sm.u.p2.d12[j];
    }
    __syncthreads();
    for (int p = tid; p < 1024; p += 256) {   // att[i][j], softmax over q, keep q==t
        int i = p >> 5, j = p & 31;
        float e[4], mxv = -1e30f;
#pragma unroll
        for (int q = 0; q < 4; ++q) {
            e[q] = lrelu(sm.u.p2.e[q][0][i] + sm.u.p2.e[q][1][j]);
            mxv = fmaxf(mxv, e[q]);
        }
        float ssum = 0.f;
#pragma unroll
        for (int q = 0; q < 4; ++q) { e[q] = expf(e[q] - mxv); ssum += e[q]; }
        sm.u.p2.att[p] = e[t] / ssum;
    }
    __syncthreads();
    float* Cb = Cbuf + ((size_t)(hd * 4 + n) * 4 + t) * 1024;
    for (int p = tid; p < 1024; p += 256) {
        int j = p >> 5, u2 = p & 31;
        float c = 0.f;
        for (int i = 0; i < 32; ++i)
            c = fmaf(sm.u.p2.att[i * 32 + j], sm.u.p2.adj[i * 32 + u2], c);
        gstore(&Cb[p], c);
    }
}

// ---------------------------------------------------------------------------
// P3 (all blocks, (n,t,s)): out rows = 0.25 * sum_hd elu(Wh_row . C_hd) for all
// 4 output t. C staged transposed + XOR-swizzled in LDS (float4, ~2-way banks).
// Layer 1 writes into xb (becomes layer-2 input); layer 2 writes global out.
// ---------------------------------------------------------------------------
__device__ void phase3(int n, int t, int s, int layer,
                       const float* __restrict__ Cbuf,
                       float* __restrict__ outg,
                       SMem& sm) {
    int tid = threadIdx.x;
    int sub = tid >> 5, u = tid & 31;
    for (int tout = 0; tout < 4; ++tout) {
        __syncthreads();
        for (int p = tid; p < 4096; p += 256) {
            int hd = p >> 10, q = p & 1023, uu = q >> 5, j = q & 31;
            float cv = gload(&Cbuf[((size_t)(hd * 4 + n) * 4 + tout) * 1024 + j * 32 + uu]);
            sm.u.p3.C[hd][uu * 32 + ((((j >> 2) ^ (uu & 7)) << 2) | (j & 3))] = cv;
        }
        __syncthreads();
        float acc0 = 0.f, acc1 = 0.f, acc2 = 0.f;
#pragma unroll
        for (int hd = 0; hd < 4; ++hd) {
            float4 cq[8];
#pragma unroll
            for (int jq = 0; jq < 8; ++jq)
                cq[jq] = *(const float4*)&sm.u.p3.C[hd][u * 32 + ((jq ^ (u & 7)) << 2)];
            float d0 = 0.f, d1 = 0.f, d2 = 0.f;
#pragma unroll
            for (int jq = 0; jq < 8; ++jq) {
                float4 w0 = *(const float4*)&sm.Wh[hd][tout][sub][jq << 2];
                float4 w1 = *(const float4*)&sm.Wh[hd][tout][sub + 8][jq << 2];
                d0 = fmaf(cq[jq].x, w0.x, d0); d0 = fmaf(cq[jq].y, w0.y, d0);
                d0 = fmaf(cq[jq].z, w0.z, d0); d0 = fmaf(cq[jq].w, w0.w, d0);
                d1 = fmaf(cq[jq].x, w1.x, d1); d1 = fmaf(cq[jq].y, w1.y, d1);
                d1 = fmaf(cq[jq].z, w1.z, d1); d1 = fmaf(cq[jq].w, w1.w, d1);
            }
            if (sub < 2) {
#pragma unroll
                for (int jq = 0; jq < 8; ++jq) {
                    float4 w2 = *(const float4*)&sm.Wh[hd][tout][sub + 16][jq << 2];
                    d2 = fmaf(cq[jq].x, w2.x, d2); d2 = fmaf(cq[jq].y, w2.y, d2);
                    d2 = fmaf(cq[jq].z, w2.z, d2); d2 = fmaf(cq[jq].w, w2.w, d2);
                }
            }
            acc0 += elu1(d0); acc1 += elu1(d1);
            if (sub < 2) acc2 += elu1(d2);
        }
        if (layer == 0) {
            sm.xb[sub][tout][u]     = 0.25f * acc0;
            sm.xb[sub + 8][tout][u] = 0.25f * acc1;
            if (sub < 2) sm.xb[sub + 16][tout][u] = 0.25f * acc2;
        } else {
            int mbase = t * 144 + s * 18;
            outg[((size_t)(n * MM + mbase + sub) * 4 + tout) * 32 + u]     = 0.25f * acc0;
            outg[((size_t)(n * MM + mbase + sub + 8) * 4 + tout) * 32 + u] = 0.25f * acc1;
            if (sub < 2)
                outg[((size_t)(n * MM + mbase + sub + 16) * 4 + tout) * 32 + u] = 0.25f * acc2;
        }
    }
}

// ---------------------------------------------------------------------------
__global__ __launch_bounds__(256) void fused_kernel(const float* __restrict__ x,
                                                    const float* __restrict__ map_w,
                                                    const float* __restrict__ map_b,
                                                    const float* __restrict__ a_temp,
                                                    const float* __restrict__ Bp,
                                                    float* __restrict__ out,
                                                    float* __restrict__ ws,
                                                    unsigned* __restrict__ cnt) {
    __shared__ SMem sm;
    float* epart = ws;               // 2 layers x 32768 floats
    float* Cbuf  = ws + 65536;       // 2 layers x 16384 floats
    int b = blockIdx.x;
    int n = b >> 5, t = (b >> 3) & 3, s = b & 7;
    int hd2 = b >> 4, n2 = (b >> 2) & 3, t2 = b & 3;

    phase1(n, t, s, x, map_w, map_b, a_temp, epart, sm);
    grid_barrier(cnt, NBLK);
    if (b < 64) phase2(hd2, n2, t2, 0, Bp, epart, Cbuf, sm);
    grid_barrier(cnt, 2 * NBLK);
    phase3(n, t, s, 0, Cbuf, out, sm);
    phase1(n, t, s, nullptr, map_w + 64, map_b + 16, a_temp + 4608, epart + 32768, sm);
    grid_barrier(cnt, 3 * NBLK);
    if (b < 64) phase2(hd2, n2, t2, 1, Bp, epart + 32768, Cbuf + 16384, sm);
    grid_barrier(cnt, 4 * NBLK);
    phase3(n, t, s, 1, Cbuf + 16384, out, sm);
}

// ---------------------------------------------------------------------------
extern "C" void kernel_launch(void* const* d_in, const int* in_sizes, int n_in,
                              void* d_out, int out_size, void* d_ws, size_t ws_size,
                              hipStream_t stream) {
    const float* x      = (const float*)d_in[0];
    const float* map_w  = (const float*)d_in[1];
    const float* map_b  = (const float*)d_in[2];
    const float* a_temp = (const float*)d_in[3];
    const float* Bp     = (const float*)d_in[4];
    float* out = (float*)d_out;
    float* ws  = (float*)d_ws;

    unsigned* cnt = (unsigned*)((char*)d_ws + (4 << 20));   // far from data
    hipMemsetAsync(cnt, 0, 64, stream);
    fused_kernel<<<NBLK, 256, 0, stream>>>(x, map_w, map_b, a_temp, Bp, out, ws, cnt);
}